// Round 2
// baseline (433.168 us; speedup 1.0000x reference)
//
#include <hip/hip_runtime.h>
#include <hip/hip_bf16.h>

// Elementwise: out = (x + 2) * 3 / 2, fp32, 8192*8192 = 67108864 elements.
// Memory-bound: 512 MB total traffic -> ~81 us at 6.3 TB/s achievable.

__global__ void fused_affine_kernel(const float* __restrict__ in,
                                    float* __restrict__ out,
                                    int n4) {
    // n4 = number of float4 elements
    const float4* __restrict__ in4 = reinterpret_cast<const float4*>(in);
    float4* __restrict__ out4 = reinterpret_cast<float4*>(out);

    int stride = gridDim.x * blockDim.x;
    for (int i = blockIdx.x * blockDim.x + threadIdx.x; i < n4; i += stride) {
        float4 v = in4[i];
        float4 r;
        // (x + 2) * 3 / 2 — keep the reference's op order for bit-faithfulness.
        r.x = ((v.x + 2.0f) * 3.0f) * 0.5f;
        r.y = ((v.y + 2.0f) * 3.0f) * 0.5f;
        r.z = ((v.z + 2.0f) * 3.0f) * 0.5f;
        r.w = ((v.w + 2.0f) * 3.0f) * 0.5f;
        out4[i] = r;
    }
}

__global__ void fused_affine_tail(const float* __restrict__ in,
                                  float* __restrict__ out,
                                  int start, int n) {
    int i = start + blockIdx.x * blockDim.x + threadIdx.x;
    if (i < n) {
        out[i] = ((in[i] + 2.0f) * 3.0f) * 0.5f;
    }
}

extern "C" void kernel_launch(void* const* d_in, const int* in_sizes, int n_in,
                              void* d_out, int out_size, void* d_ws, size_t ws_size,
                              hipStream_t stream) {
    const float* in = (const float*)d_in[0];
    float* out = (float*)d_out;
    int n = in_sizes[0];          // 67108864
    int n4 = n / 4;               // vectorized count
    int tail_start = n4 * 4;

    const int block = 256;
    // 256 CUs * 8 blocks/CU = 2048 blocks; grid-stride covers the rest.
    int grid = (n4 + block - 1) / block;
    if (grid > 2048) grid = 2048;

    fused_affine_kernel<<<grid, block, 0, stream>>>(in, out, n4);

    if (tail_start < n) {
        int tail_n = n - tail_start;
        int tgrid = (tail_n + block - 1) / block;
        fused_affine_tail<<<tgrid, block, 0, stream>>>(in, out, tail_start, n);
    }
}